// Round 1
// baseline (5563.286 us; speedup 1.0000x reference)
//
#include <hip/hip_runtime.h>

#define N_NODES 100000
#define N_EDGES 1600000
#define N_LABEL 200000
#define D 128

// ---------------- prep: w = rowsum(lin_W), c = sum(lin_b) ----------------
__global__ void k_prep(const float* __restrict__ linW, const float* __restrict__ linb,
                       float* __restrict__ wv, float* __restrict__ cval) {
    int t = threadIdx.x;  // 128 threads
    float s = 0.f;
    for (int j = 0; j < D; ++j) s += linW[t * D + j];
    wv[t] = s;
    __shared__ float red[128];
    red[t] = linb[t];
    __syncthreads();
    for (int st = 64; st > 0; st >>= 1) {
        if (t < st) red[t] += red[t + st];
        __syncthreads();
    }
    if (t == 0) *cval = red[0];
}

// ---------------- degree / norm ----------------
__global__ void k_deg_init(float* __restrict__ deg) {
    int i = blockIdx.x * 256 + threadIdx.x;
    if (i < N_NODES) deg[i] = 1.0f;  // self loop weight
}

__global__ void k_deg_accum(const int* __restrict__ ei, const float* __restrict__ ew,
                            float* __restrict__ deg) {
    int e = blockIdx.x * 256 + threadIdx.x;
    if (e < N_EDGES) atomicAdd(&deg[ei[N_EDGES + e]], ew[e]);
}

__global__ void k_dinv(float* __restrict__ deg) {
    int i = blockIdx.x * 256 + threadIdx.x;
    if (i < N_NODES) deg[i] = rsqrtf(deg[i]);
}

__global__ void k_norm(const int* __restrict__ ei, const float* __restrict__ ew,
                       const float* __restrict__ dinv, float* __restrict__ norm) {
    int e = blockIdx.x * 256 + threadIdx.x;
    if (e < N_EDGES) norm[e] = dinv[ei[e]] * ew[e] * dinv[ei[N_EDGES + e]];
}

// ---------------- GEMM: H = X @ W  (X: [N,128], W: [128,128]) ----------------
__global__ __launch_bounds__(256) void k_gemm(const float* __restrict__ X,
                                              const float* __restrict__ W,
                                              float* __restrict__ H) {
    __shared__ float xs[64][128];
    __shared__ float ws[16][128];
    int tid = threadIdx.x;
    int rowBase = blockIdx.x * 64;

    // stage 64 x-rows (guarded)
#pragma unroll
    for (int i = 0; i < 8; ++i) {
        int idx = tid + i * 256;          // float4 index 0..2047
        int r = idx >> 5;                 // 32 float4 per row
        int cc = (idx & 31) * 4;
        int gr = rowBase + r;
        float4 v = make_float4(0.f, 0.f, 0.f, 0.f);
        if (gr < N_NODES) v = *(const float4*)&X[(size_t)gr * D + cc];
        *(float4*)&xs[r][cc] = v;
    }

    int rg = tid >> 5;       // 0..7  (row group of 8)
    int cg = tid & 31;       // 0..31 (col group of 4)
    int c0 = cg * 4;
    float acc[8][4] = {};

    for (int k0 = 0; k0 < D; k0 += 16) {
        __syncthreads();  // protect ws reuse (also covers xs staging on first iter)
#pragma unroll
        for (int i = 0; i < 2; ++i) {
            int idx = tid + i * 256;      // float4 idx 0..511
            int r = idx >> 5;
            int cc = (idx & 31) * 4;
            *(float4*)&ws[r][cc] = *(const float4*)&W[(k0 + r) * D + cc];
        }
        __syncthreads();
#pragma unroll
        for (int kk = 0; kk < 16; ++kk) {
            float4 w4 = *(float4*)&ws[kk][c0];
#pragma unroll
            for (int r = 0; r < 8; ++r) {
                float xv = xs[rg * 8 + r][k0 + kk];
                acc[r][0] += xv * w4.x;
                acc[r][1] += xv * w4.y;
                acc[r][2] += xv * w4.z;
                acc[r][3] += xv * w4.w;
            }
        }
    }

#pragma unroll
    for (int r = 0; r < 8; ++r) {
        int gr = rowBase + rg * 8 + r;
        if (gr < N_NODES)
            *(float4*)&H[(size_t)gr * D + c0] =
                make_float4(acc[r][0], acc[r][1], acc[r][2], acc[r][3]);
    }
}

// ---------------- aggregation ----------------
// out[i] = h[i] * dinv[i]^2   (self loop term; also zero-initializes out)
__global__ void k_self(const float* __restrict__ h, const float* __restrict__ dinv,
                       float* __restrict__ out) {
    int i = blockIdx.x * 256 + threadIdx.x;  // float4 index
    if (i < N_NODES * (D / 4)) {
        int node = i >> 5;
        float sn = dinv[node];
        sn *= sn;
        float4 v = ((const float4*)h)[i];
        v.x *= sn; v.y *= sn; v.z *= sn; v.w *= sn;
        ((float4*)out)[i] = v;
    }
}

// out[dst] += norm[e] * h[src]   (32 threads per edge, 4 feats each)
__global__ void k_edges(const int* __restrict__ ei, const float* __restrict__ norm,
                        const float* __restrict__ h, float* __restrict__ out) {
    unsigned g = blockIdx.x * 256 + threadIdx.x;
    int e = g >> 5;
    int t = g & 31;
    if (e < N_EDGES) {
        int s = ei[e];
        int d = ei[N_EDGES + e];
        float nm = norm[e];
        float4 v = *(const float4*)&h[(size_t)s * D + t * 4];
        float* od = &out[(size_t)d * D + t * 4];
        atomicAdd(od + 0, v.x * nm);
        atomicAdd(od + 1, v.y * nm);
        atomicAdd(od + 2, v.z * nm);
        atomicAdd(od + 3, v.w * nm);
    }
}

__global__ void k_bias_relu(float* __restrict__ out, const float* __restrict__ b) {
    int i = blockIdx.x * 256 + threadIdx.x;  // float4 index
    if (i < N_NODES * (D / 4)) {
        int cc = (i & 31) * 4;
        float4 bb = *(const float4*)&b[cc];
        float4 v = ((float4*)out)[i];
        v.x = fmaxf(v.x + bb.x, 0.f);
        v.y = fmaxf(v.y + bb.y, 0.f);
        v.z = fmaxf(v.z + bb.z, 0.f);
        v.w = fmaxf(v.w + bb.w, 0.f);
        ((float4*)out)[i] = v;
    }
}

// ---------------- final: res[l] = sum_k out[a][k]*out[b][k]*w[k] + c ----------------
__global__ void k_final(const int* __restrict__ eli, const float* __restrict__ o2,
                        const float* __restrict__ wv, const float* __restrict__ cval,
                        float* __restrict__ res) {
    unsigned g = blockIdx.x * 256 + threadIdx.x;
    int l = g >> 6;       // wave per label pair
    int t = g & 63;
    if (l < N_LABEL) {
        int a = eli[l];
        int b = eli[N_LABEL + l];
        int f = t * 2;
        float2 va = *(const float2*)&o2[(size_t)a * D + f];
        float2 vb = *(const float2*)&o2[(size_t)b * D + f];
        float2 w2 = *(const float2*)&wv[f];
        float s = va.x * vb.x * w2.x + va.y * vb.y * w2.y;
#pragma unroll
        for (int st = 32; st > 0; st >>= 1) s += __shfl_down(s, st, 64);
        if (t == 0) res[l] = s + *cval;
    }
}

extern "C" void kernel_launch(void* const* d_in, const int* in_sizes, int n_in,
                              void* d_out, int out_size, void* d_ws, size_t ws_size,
                              hipStream_t stream) {
    const float* x    = (const float*)d_in[0];
    const int*   ei   = (const int*)d_in[1];
    const float* ew   = (const float*)d_in[2];
    const int*   eli  = (const int*)d_in[3];
    const float* W1   = (const float*)d_in[4];
    const float* b1   = (const float*)d_in[5];
    const float* W2   = (const float*)d_in[6];
    const float* b2   = (const float*)d_in[7];
    const float* linW = (const float*)d_in[8];
    const float* linb = (const float*)d_in[9];
    float* res = (float*)d_out;

    float* ws   = (float*)d_ws;
    float* dinv = ws;                       // N
    float* norm = dinv + N_NODES;           // E
    float* h    = norm + N_EDGES;           // N*D
    float* agg  = h + (size_t)N_NODES * D;  // N*D
    float* wv   = agg + (size_t)N_NODES * D;// D
    float* cval = wv + D;                   // 1

    k_prep<<<1, 128, 0, stream>>>(linW, linb, wv, cval);
    k_deg_init<<<(N_NODES + 255) / 256, 256, 0, stream>>>(dinv);
    k_deg_accum<<<(N_EDGES + 255) / 256, 256, 0, stream>>>(ei, ew, dinv);
    k_dinv<<<(N_NODES + 255) / 256, 256, 0, stream>>>(dinv);
    k_norm<<<(N_EDGES + 255) / 256, 256, 0, stream>>>(ei, ew, dinv, norm);

    // layer 1
    k_gemm<<<(N_NODES + 63) / 64, 256, 0, stream>>>(x, W1, h);
    k_self<<<(N_NODES * (D / 4) + 255) / 256, 256, 0, stream>>>(h, dinv, agg);
    k_edges<<<N_EDGES / 8, 256, 0, stream>>>(ei, norm, h, agg);
    k_bias_relu<<<(N_NODES * (D / 4) + 255) / 256, 256, 0, stream>>>(agg, b1);

    // layer 2
    k_gemm<<<(N_NODES + 63) / 64, 256, 0, stream>>>(agg, W2, h);
    k_self<<<(N_NODES * (D / 4) + 255) / 256, 256, 0, stream>>>(h, dinv, agg);
    k_edges<<<N_EDGES / 8, 256, 0, stream>>>(ei, norm, h, agg);
    k_bias_relu<<<(N_NODES * (D / 4) + 255) / 256, 256, 0, stream>>>(agg, b2);

    // final
    k_final<<<(N_LABEL * 64 + 255) / 256, 256, 0, stream>>>(eli, agg, wv, cval, res);
}

// Round 2
// 766.512 us; speedup vs baseline: 7.2579x; 7.2579x over previous
//
#include <hip/hip_runtime.h>

#define N_NODES 100000
#define N_EDGES 1600000
#define N_LABEL 200000
#define D 128

#define SCAN_BLOCKS ((N_NODES + 255) / 256)   // 391

// ---------------- prep: w = rowsum(lin_W), c = sum(lin_b) ----------------
__global__ void k_prep(const float* __restrict__ linW, const float* __restrict__ linb,
                       float* __restrict__ wv, float* __restrict__ cval) {
    int t = threadIdx.x;  // 128 threads
    float s = 0.f;
    for (int j = 0; j < D; ++j) s += linW[t * D + j];
    wv[t] = s;
    __shared__ float red[128];
    red[t] = linb[t];
    __syncthreads();
    for (int st = 64; st > 0; st >>= 1) {
        if (t < st) red[t] += red[t + st];
        __syncthreads();
    }
    if (t == 0) *cval = red[0];
}

// ---------------- degree / norm ----------------
__global__ void k_deg_init(float* __restrict__ deg) {
    int i = blockIdx.x * 256 + threadIdx.x;
    if (i < N_NODES) deg[i] = 1.0f;  // self loop weight
}

__global__ void k_deg_accum(const int* __restrict__ ei, const float* __restrict__ ew,
                            float* __restrict__ deg) {
    int e = blockIdx.x * 256 + threadIdx.x;
    if (e < N_EDGES) atomicAdd(&deg[ei[N_EDGES + e]], ew[e]);
}

__global__ void k_dinv(float* __restrict__ deg) {
    int i = blockIdx.x * 256 + threadIdx.x;
    if (i < N_NODES) deg[i] = rsqrtf(deg[i]);
}

// ---------------- CSR build ----------------
__global__ void k_zero_int(int* __restrict__ p, int n) {
    int i = blockIdx.x * 256 + threadIdx.x;
    if (i < n) p[i] = 0;
}

__global__ void k_count(const int* __restrict__ ei, int* __restrict__ cnt) {
    int e = blockIdx.x * 256 + threadIdx.x;
    if (e < N_EDGES) atomicAdd(&cnt[ei[N_EDGES + e]], 1);
}

// in-place exclusive scan, phase 1: per-block scan + block totals
__global__ void k_scan1(int* __restrict__ offs, int* __restrict__ bsum) {
    __shared__ int sm[256];
    int tid = threadIdx.x;
    int i = blockIdx.x * 256 + tid;
    int v = (i < N_NODES) ? offs[i] : 0;
    sm[tid] = v;
    __syncthreads();
    for (int st = 1; st < 256; st <<= 1) {
        int add = (tid >= st) ? sm[tid - st] : 0;
        __syncthreads();
        sm[tid] += add;
        __syncthreads();
    }
    if (i < N_NODES) offs[i] = sm[tid] - v;  // exclusive
    if (tid == 255) bsum[blockIdx.x] = sm[255];
}

// phase 2: scan block totals (single block, 512 >= SCAN_BLOCKS)
__global__ void k_scan2(int* __restrict__ bsum) {
    __shared__ int sm[512];
    int tid = threadIdx.x;
    int v = (tid < SCAN_BLOCKS) ? bsum[tid] : 0;
    sm[tid] = v;
    __syncthreads();
    for (int st = 1; st < 512; st <<= 1) {
        int add = (tid >= st) ? sm[tid - st] : 0;
        __syncthreads();
        sm[tid] += add;
        __syncthreads();
    }
    if (tid < SCAN_BLOCKS) bsum[tid] = sm[tid] - v;  // exclusive
}

// phase 3: add block offsets; set sentinel
__global__ void k_scan3(int* __restrict__ offs, const int* __restrict__ bsum) {
    int i = blockIdx.x * 256 + threadIdx.x;
    if (i < N_NODES) offs[i] += bsum[i >> 8];
    if (i == 0) offs[N_NODES] = N_EDGES;
}

// scatter edges into CSR, computing norm on the fly
__global__ void k_scatter(const int* __restrict__ ei, const float* __restrict__ ew,
                          const float* __restrict__ dinv, const int* __restrict__ offs,
                          int* __restrict__ fill, int* __restrict__ csr_src,
                          float* __restrict__ csr_w) {
    int e = blockIdx.x * 256 + threadIdx.x;
    if (e < N_EDGES) {
        int s = ei[e];
        int d = ei[N_EDGES + e];
        float nm = dinv[s] * ew[e] * dinv[d];
        int pos = offs[d] + atomicAdd(&fill[d], 1);
        csr_src[pos] = s;
        csr_w[pos] = nm;
    }
}

// ---------------- GEMM: H = X @ W  (X: [N,128], W: [128,128]) ----------------
__global__ __launch_bounds__(256) void k_gemm(const float* __restrict__ X,
                                              const float* __restrict__ W,
                                              float* __restrict__ H) {
    __shared__ float xs[64][128];
    __shared__ float ws[16][128];
    int tid = threadIdx.x;
    int rowBase = blockIdx.x * 64;

#pragma unroll
    for (int i = 0; i < 8; ++i) {
        int idx = tid + i * 256;
        int r = idx >> 5;
        int cc = (idx & 31) * 4;
        int gr = rowBase + r;
        float4 v = make_float4(0.f, 0.f, 0.f, 0.f);
        if (gr < N_NODES) v = *(const float4*)&X[(size_t)gr * D + cc];
        *(float4*)&xs[r][cc] = v;
    }

    int rg = tid >> 5;
    int cg = tid & 31;
    int c0 = cg * 4;
    float acc[8][4] = {};

    for (int k0 = 0; k0 < D; k0 += 16) {
        __syncthreads();
#pragma unroll
        for (int i = 0; i < 2; ++i) {
            int idx = tid + i * 256;
            int r = idx >> 5;
            int cc = (idx & 31) * 4;
            *(float4*)&ws[r][cc] = *(const float4*)&W[(k0 + r) * D + cc];
        }
        __syncthreads();
#pragma unroll
        for (int kk = 0; kk < 16; ++kk) {
            float4 w4 = *(float4*)&ws[kk][c0];
#pragma unroll
            for (int r = 0; r < 8; ++r) {
                float xv = xs[rg * 8 + r][k0 + kk];
                acc[r][0] += xv * w4.x;
                acc[r][1] += xv * w4.y;
                acc[r][2] += xv * w4.z;
                acc[r][3] += xv * w4.w;
            }
        }
    }

#pragma unroll
    for (int r = 0; r < 8; ++r) {
        int gr = rowBase + rg * 8 + r;
        if (gr < N_NODES)
            *(float4*)&H[(size_t)gr * D + c0] =
                make_float4(acc[r][0], acc[r][1], acc[r][2], acc[r][3]);
    }
}

// ---------------- fused aggregation: self + gather + bias + relu ----------------
// one wave per node, float2 per lane
__global__ __launch_bounds__(256) void k_agg(const float* __restrict__ h,
                                             const float* __restrict__ dinv,
                                             const int* __restrict__ offs,
                                             const int* __restrict__ csr_src,
                                             const float* __restrict__ csr_w,
                                             const float* __restrict__ bias,
                                             float* __restrict__ out) {
    int wid = threadIdx.x >> 6;
    int lane = threadIdx.x & 63;
    int node = blockIdx.x * 4 + wid;
    if (node >= N_NODES) return;
    int f = lane * 2;
    float dn = dinv[node];
    dn *= dn;
    float2 v = *(const float2*)&h[(size_t)node * D + f];
    float ax = v.x * dn, ay = v.y * dn;
    int p0 = offs[node], p1 = offs[node + 1];
    for (int p = p0; p < p1; ++p) {
        int s = csr_src[p];
        float w = csr_w[p];
        float2 hv = *(const float2*)&h[(size_t)s * D + f];
        ax += w * hv.x;
        ay += w * hv.y;
    }
    float2 bb = *(const float2*)&bias[f];
    ax = fmaxf(ax + bb.x, 0.f);
    ay = fmaxf(ay + bb.y, 0.f);
    *(float2*)&out[(size_t)node * D + f] = make_float2(ax, ay);
}

// ---------------- final: res[l] = sum_k out[a][k]*out[b][k]*w[k] + c ----------------
__global__ void k_final(const int* __restrict__ eli, const float* __restrict__ o2,
                        const float* __restrict__ wv, const float* __restrict__ cval,
                        float* __restrict__ res) {
    unsigned g = blockIdx.x * 256 + threadIdx.x;
    int l = g >> 6;
    int t = g & 63;
    if (l < N_LABEL) {
        int a = eli[l];
        int b = eli[N_LABEL + l];
        int f = t * 2;
        float2 va = *(const float2*)&o2[(size_t)a * D + f];
        float2 vb = *(const float2*)&o2[(size_t)b * D + f];
        float2 w2 = *(const float2*)&wv[f];
        float s = va.x * vb.x * w2.x + va.y * vb.y * w2.y;
#pragma unroll
        for (int st = 32; st > 0; st >>= 1) s += __shfl_down(s, st, 64);
        if (t == 0) res[l] = s + *cval;
    }
}

extern "C" void kernel_launch(void* const* d_in, const int* in_sizes, int n_in,
                              void* d_out, int out_size, void* d_ws, size_t ws_size,
                              hipStream_t stream) {
    const float* x    = (const float*)d_in[0];
    const int*   ei   = (const int*)d_in[1];
    const float* ew   = (const float*)d_in[2];
    const int*   eli  = (const int*)d_in[3];
    const float* W1   = (const float*)d_in[4];
    const float* b1   = (const float*)d_in[5];
    const float* W2   = (const float*)d_in[6];
    const float* b2   = (const float*)d_in[7];
    const float* linW = (const float*)d_in[8];
    const float* linb = (const float*)d_in[9];
    float* res = (float*)d_out;

    // workspace layout (padded so h is 16B-aligned)
    float* ws      = (float*)d_ws;
    float* dinv    = ws;                              // N            (100000)
    int*   offs    = (int*)(dinv + N_NODES);          // N+4          (100004)
    int*   fill    = offs + N_NODES + 4;              // N            (100000)
    int*   bsum    = fill + N_NODES;                  // 512
    int*   csr_src = bsum + 512;                      // E            (1600000)
    float* csr_w   = (float*)(csr_src + N_EDGES);     // E            (1600000)
    float* h       = csr_w + N_EDGES;                 // N*D
    float* agg     = h + (size_t)N_NODES * D;         // N*D
    float* wv      = agg + (size_t)N_NODES * D;       // D
    float* cval    = wv + D;                          // 1

    k_prep<<<1, 128, 0, stream>>>(linW, linb, wv, cval);

    // degrees -> dinv
    k_deg_init<<<(N_NODES + 255) / 256, 256, 0, stream>>>(dinv);
    k_deg_accum<<<(N_EDGES + 255) / 256, 256, 0, stream>>>(ei, ew, dinv);
    k_dinv<<<(N_NODES + 255) / 256, 256, 0, stream>>>(dinv);

    // CSR build (counts in offs, scanned in place)
    k_zero_int<<<(2 * N_NODES + 4 + 255) / 256, 256, 0, stream>>>(offs, 2 * N_NODES + 4);
    k_count<<<(N_EDGES + 255) / 256, 256, 0, stream>>>(ei, offs);
    k_scan1<<<SCAN_BLOCKS, 256, 0, stream>>>(offs, bsum);
    k_scan2<<<1, 512, 0, stream>>>(bsum);
    k_scan3<<<SCAN_BLOCKS, 256, 0, stream>>>(offs, bsum);
    k_scatter<<<(N_EDGES + 255) / 256, 256, 0, stream>>>(ei, ew, dinv, offs, fill,
                                                         csr_src, csr_w);

    // layer 1
    k_gemm<<<(N_NODES + 63) / 64, 256, 0, stream>>>(x, W1, h);
    k_agg<<<(N_NODES + 3) / 4, 256, 0, stream>>>(h, dinv, offs, csr_src, csr_w, b1, agg);

    // layer 2
    k_gemm<<<(N_NODES + 63) / 64, 256, 0, stream>>>(agg, W2, h);
    k_agg<<<(N_NODES + 3) / 4, 256, 0, stream>>>(h, dinv, offs, csr_src, csr_w, b2, agg);

    // final
    k_final<<<(N_LABEL * 64 + 255) / 256, 256, 0, stream>>>(eli, agg, wv, cval, res);
}

// Round 4
// 747.614 us; speedup vs baseline: 7.4414x; 1.0253x over previous
//
#include <hip/hip_runtime.h>

#define N_NODES 100000
#define N_EDGES 1600000
#define N_LABEL 200000
#define D 128

#define SCAN_BLOCKS ((N_NODES + 255) / 256)   // 391

// ---- bf16 helpers (round-to-nearest-even) ----
static __device__ __forceinline__ unsigned short f2bf(float f) {
    unsigned u = __float_as_uint(f);
    u += 0x7fffu + ((u >> 16) & 1u);
    return (unsigned short)(u >> 16);
}
static __device__ __forceinline__ float bf2f_lo(unsigned p) {
    return __uint_as_float(p << 16);
}
static __device__ __forceinline__ float bf2f_hi(unsigned p) {
    return __uint_as_float(p & 0xffff0000u);
}

// ---------------- prep: w = rowsum(lin_W), c = sum(lin_b) ----------------
__global__ void k_prep(const float* __restrict__ linW, const float* __restrict__ linb,
                       float* __restrict__ wv, float* __restrict__ cval) {
    int t = threadIdx.x;  // 128 threads
    float s = 0.f;
    for (int j = 0; j < D; ++j) s += linW[t * D + j];
    wv[t] = s;
    __shared__ float red[128];
    red[t] = linb[t];
    __syncthreads();
    for (int st = 64; st > 0; st >>= 1) {
        if (t < st) red[t] += red[t + st];
        __syncthreads();
    }
    if (t == 0) *cval = red[0];
}

// ---------------- init: deg=1 (self loop), offs=0, fill=0 ----------------
__global__ void k_init(float* __restrict__ deg, int* __restrict__ offs,
                       int* __restrict__ fill) {
    int i = blockIdx.x * 256 + threadIdx.x;
    if (i < N_NODES) { deg[i] = 1.0f; fill[i] = 0; }
    if (i < N_NODES + 4) offs[i] = 0;
}

// fused: degree accumulate + in-degree count (one pass over edge index)
__global__ void k_countdeg(const int* __restrict__ ei, const float* __restrict__ ew,
                           float* __restrict__ deg, int* __restrict__ cnt) {
    int e = blockIdx.x * 256 + threadIdx.x;
    if (e < N_EDGES) {
        int d = ei[N_EDGES + e];
        atomicAdd(&deg[d], ew[e]);
        atomicAdd(&cnt[d], 1);
    }
}

__global__ void k_dinv(float* __restrict__ deg) {
    int i = blockIdx.x * 256 + threadIdx.x;
    if (i < N_NODES) deg[i] = rsqrtf(deg[i]);
}

// ---------------- CSR build: scan ----------------
__global__ void k_scan1(int* __restrict__ offs, int* __restrict__ bsum) {
    __shared__ int sm[256];
    int tid = threadIdx.x;
    int i = blockIdx.x * 256 + tid;
    int v = (i < N_NODES) ? offs[i] : 0;
    sm[tid] = v;
    __syncthreads();
    for (int st = 1; st < 256; st <<= 1) {
        int add = (tid >= st) ? sm[tid - st] : 0;
        __syncthreads();
        sm[tid] += add;
        __syncthreads();
    }
    if (i < N_NODES) offs[i] = sm[tid] - v;  // exclusive
    if (tid == 255) bsum[blockIdx.x] = sm[255];
}

__global__ void k_scan2(int* __restrict__ bsum) {
    __shared__ int sm[512];
    int tid = threadIdx.x;
    int v = (tid < SCAN_BLOCKS) ? bsum[tid] : 0;
    sm[tid] = v;
    __syncthreads();
    for (int st = 1; st < 512; st <<= 1) {
        int add = (tid >= st) ? sm[tid - st] : 0;
        __syncthreads();
        sm[tid] += add;
        __syncthreads();
    }
    if (tid < SCAN_BLOCKS) bsum[tid] = sm[tid] - v;  // exclusive
}

__global__ void k_scan3(int* __restrict__ offs, const int* __restrict__ bsum) {
    int i = blockIdx.x * 256 + threadIdx.x;
    if (i < N_NODES) offs[i] += bsum[i >> 8];
    if (i == 0) offs[N_NODES] = N_EDGES;
}

// scatter edges into CSR, computing norm on the fly
__global__ void k_scatter(const int* __restrict__ ei, const float* __restrict__ ew,
                          const float* __restrict__ dinv, const int* __restrict__ offs,
                          int* __restrict__ fill, int* __restrict__ csr_src,
                          float* __restrict__ csr_w) {
    int e = blockIdx.x * 256 + threadIdx.x;
    if (e < N_EDGES) {
        int s = ei[e];
        int d = ei[N_EDGES + e];
        float nm = dinv[s] * ew[e] * dinv[d];
        int pos = offs[d] + atomicAdd(&fill[d], 1);
        csr_src[pos] = s;
        csr_w[pos] = nm;
    }
}

// ---------------- GEMM: H(bf16) = X(f32) @ W(f32) ----------------
__global__ __launch_bounds__(256) void k_gemm(const float* __restrict__ X,
                                              const float* __restrict__ W,
                                              unsigned short* __restrict__ H) {
    __shared__ float xs[64][128];
    __shared__ float ws[16][128];
    int tid = threadIdx.x;
    int rowBase = blockIdx.x * 64;

#pragma unroll
    for (int i = 0; i < 8; ++i) {
        int idx = tid + i * 256;
        int r = idx >> 5;
        int cc = (idx & 31) * 4;
        int gr = rowBase + r;
        float4 v = make_float4(0.f, 0.f, 0.f, 0.f);
        if (gr < N_NODES) v = *(const float4*)&X[(size_t)gr * D + cc];
        *(float4*)&xs[r][cc] = v;
    }

    int rg = tid >> 5;       // 0..7
    int cg = tid & 31;       // 0..31
    int c0 = cg * 4;
    float acc[8][4] = {};

    for (int k0 = 0; k0 < D; k0 += 16) {
        __syncthreads();  // protect ws reuse (covers xs staging on first iter)
#pragma unroll
        for (int i = 0; i < 2; ++i) {
            int idx = tid + i * 256;
            int r = idx >> 5;
            int cc = (idx & 31) * 4;
            *(float4*)&ws[r][cc] = *(const float4*)&W[(k0 + r) * D + cc];
        }
        __syncthreads();
#pragma unroll
        for (int kk = 0; kk < 16; kk += 4) {
            float4 w0 = *(float4*)&ws[kk + 0][c0];
            float4 w1 = *(float4*)&ws[kk + 1][c0];
            float4 w2 = *(float4*)&ws[kk + 2][c0];
            float4 w3 = *(float4*)&ws[kk + 3][c0];
#pragma unroll
            for (int r = 0; r < 8; ++r) {
                float4 xv = *(float4*)&xs[rg * 8 + r][k0 + kk];
                acc[r][0] += xv.x * w0.x + xv.y * w1.x + xv.z * w2.x + xv.w * w3.x;
                acc[r][1] += xv.x * w0.y + xv.y * w1.y + xv.z * w2.y + xv.w * w3.y;
                acc[r][2] += xv.x * w0.z + xv.y * w1.z + xv.z * w2.z + xv.w * w3.z;
                acc[r][3] += xv.x * w0.w + xv.y * w1.w + xv.z * w2.w + xv.w * w3.w;
            }
        }
    }

#pragma unroll
    for (int r = 0; r < 8; ++r) {
        int gr = rowBase + rg * 8 + r;
        if (gr < N_NODES) {
            ushort4 o;
            o.x = f2bf(acc[r][0]);
            o.y = f2bf(acc[r][1]);
            o.z = f2bf(acc[r][2]);
            o.w = f2bf(acc[r][3]);
            *(ushort4*)&H[(size_t)gr * D + c0] = o;
        }
    }
}

// ---------------- fused aggregation: self + gather + bias + relu ----------------
// one wave per node; h is bf16 (uint = 2 feats per lane); accumulate fp32
template <bool OUT_BF>
__global__ __launch_bounds__(256) void k_agg(const unsigned* __restrict__ h,
                                             const float* __restrict__ dinv,
                                             const int* __restrict__ offs,
                                             const int* __restrict__ csr_src,
                                             const float* __restrict__ csr_w,
                                             const float* __restrict__ bias,
                                             void* __restrict__ out) {
    int wid = threadIdx.x >> 6;
    int lane = threadIdx.x & 63;
    int node = blockIdx.x * 4 + wid;
    if (node >= N_NODES) return;
    float dn = dinv[node];
    dn *= dn;
    unsigned sv = h[(size_t)node * 64 + lane];
    float ax = bf2f_lo(sv) * dn, ay = bf2f_hi(sv) * dn;
    int p0 = offs[node], p1 = offs[node + 1];
    for (int p = p0; p < p1; ++p) {
        int s = csr_src[p];
        float w = csr_w[p];
        unsigned hv = h[(size_t)s * 64 + lane];
        ax += w * bf2f_lo(hv);
        ay += w * bf2f_hi(hv);
    }
    float2 bb = *(const float2*)&bias[lane * 2];
    ax = fmaxf(ax + bb.x, 0.f);
    ay = fmaxf(ay + bb.y, 0.f);
    if (OUT_BF) {
        unsigned o = (unsigned)f2bf(ax) | ((unsigned)f2bf(ay) << 16);
        ((unsigned*)out)[(size_t)node * 64 + lane] = o;
    } else {
        *(float2*)&((float*)out)[(size_t)node * D + lane * 2] = make_float2(ax, ay);
    }
}

// ---------------- final: res[l] = sum_k o2[a][k]*o2[b][k]*w[k] + c ----------------
__global__ void k_final(const int* __restrict__ eli, const unsigned* __restrict__ o2,
                        const float* __restrict__ wv, const float* __restrict__ cval,
                        float* __restrict__ res) {
    unsigned g = blockIdx.x * 256 + threadIdx.x;
    int l = g >> 6;
    int t = g & 63;
    if (l < N_LABEL) {
        int a = eli[l];
        int b = eli[N_LABEL + l];
        unsigned ua = o2[(size_t)a * 64 + t];
        unsigned ub = o2[(size_t)b * 64 + t];
        float2 w2 = *(const float2*)&wv[t * 2];
        float s = bf2f_lo(ua) * bf2f_lo(ub) * w2.x + bf2f_hi(ua) * bf2f_hi(ub) * w2.y;
#pragma unroll
        for (int st = 32; st > 0; st >>= 1) s += __shfl_down(s, st, 64);
        if (t == 0) res[l] = s + *cval;
    }
}

extern "C" void kernel_launch(void* const* d_in, const int* in_sizes, int n_in,
                              void* d_out, int out_size, void* d_ws, size_t ws_size,
                              hipStream_t stream) {
    const float* x    = (const float*)d_in[0];
    const int*   ei   = (const int*)d_in[1];
    const float* ew   = (const float*)d_in[2];
    const int*   eli  = (const int*)d_in[3];
    const float* W1   = (const float*)d_in[4];
    const float* b1   = (const float*)d_in[5];
    const float* W2   = (const float*)d_in[6];
    const float* b2   = (const float*)d_in[7];
    const float* linW = (const float*)d_in[8];
    const float* linb = (const float*)d_in[9];
    float* res = (float*)d_out;

    // workspace layout (16B alignment maintained for all row buffers)
    float*    ws      = (float*)d_ws;
    float*    dinv    = ws;                              // N
    int*      offs    = (int*)(dinv + N_NODES);          // N+4
    int*      fill    = offs + N_NODES + 4;              // N
    int*      bsum    = fill + N_NODES;                  // 512
    int*      csr_src = bsum + 512;                      // E
    float*    csr_w   = (float*)(csr_src + N_EDGES);     // E
    unsigned* h_bf    = (unsigned*)(csr_w + N_EDGES);    // N*64 uints (bf16 h)
    float*    agg     = (float*)(h_bf + (size_t)N_NODES * 64);   // N*D f32
    unsigned* out2    = (unsigned*)(agg + (size_t)N_NODES * D);  // N*64 uints
    float*    wv      = (float*)(out2 + (size_t)N_NODES * 64);   // D
    float*    cval    = wv + D;                          // 1

    k_prep<<<1, 128, 0, stream>>>(linW, linb, wv, cval);

    // degrees + CSR counts (fused pass), then dinv
    k_init<<<(N_NODES + 4 + 255) / 256, 256, 0, stream>>>(dinv, offs, fill);
    k_countdeg<<<(N_EDGES + 255) / 256, 256, 0, stream>>>(ei, ew, dinv, offs);
    k_dinv<<<(N_NODES + 255) / 256, 256, 0, stream>>>(dinv);

    // scan + scatter
    k_scan1<<<SCAN_BLOCKS, 256, 0, stream>>>(offs, bsum);
    k_scan2<<<1, 512, 0, stream>>>(bsum);
    k_scan3<<<SCAN_BLOCKS, 256, 0, stream>>>(offs, bsum);
    k_scatter<<<(N_EDGES + 255) / 256, 256, 0, stream>>>(ei, ew, dinv, offs, fill,
                                                         csr_src, csr_w);

    // layer 1: h = x@W1 (bf16), agg = A_norm·h + b1, relu (fp32 out)
    k_gemm<<<(N_NODES + 63) / 64, 256, 0, stream>>>(x, W1, (unsigned short*)h_bf);
    k_agg<false><<<(N_NODES + 3) / 4, 256, 0, stream>>>(h_bf, dinv, offs, csr_src,
                                                        csr_w, b1, agg);

    // layer 2: h = agg@W2 (bf16), out2 = A_norm·h + b2, relu (bf16 out)
    k_gemm<<<(N_NODES + 63) / 64, 256, 0, stream>>>(agg, W2, (unsigned short*)h_bf);
    k_agg<true><<<(N_NODES + 3) / 4, 256, 0, stream>>>(h_bf, dinv, offs, csr_src,
                                                       csr_w, b2, out2);

    // final
    k_final<<<(N_LABEL * 64 + 255) / 256, 256, 0, stream>>>(eli, out2, wv, cval, res);
}